// Round 10
// baseline (2600.201 us; speedup 1.0000x reference)
//
#include <hip/hip_runtime.h>
#include <hip/hip_bf16.h>

// ============================================================================
// PseudoLabelGenerator: round 16 — lstm occupancy tier-crossing.
//   lstm was 1 block/CU (2 waves/SIMD): ~160 unified regs/wave (w1r 40 +
//   w2r 64 + state 32 + acc 32) > 128-reg tier boundary; ~35% of its 730us
//   was stall. Shrink forced-live below 128 and force (512,4):
//     - w1r -> JIT volatile L2 loads per segment (PB1 80KB, L2-resident)
//     - w2r ks=4..7 -> JIT volatile L2 loads (ks=0..3 stay in regs)
//     - biases -> LDS table (sbias), read per segment
//     - xa -> re-read from xbuf per segment
//   Peak extra liveness per ks-group ~8 regs (loads consumed immediately).
//   Tail: 11 -> 8 launches (probs U pack U rankhist; conf U scan1; scan3
//   shrunk to rowptr-only, scatterrank adds shard prefix itself).
// ============================================================================

#define HIDN 256
#define NC 10
#define TSTEPS 12
#define NHEADS 4
#define LH 128

typedef __attribute__((ext_vector_type(8))) short short8;
typedef __attribute__((ext_vector_type(4))) float floatx4;

__device__ __forceinline__ unsigned short f2bf(float x) {
  unsigned u = __float_as_uint(x);
  u = u + 0x7FFFu + ((u >> 16) & 1u);   // round-to-nearest-even
  return (unsigned short)(u >> 16);
}
__device__ __forceinline__ unsigned char f2fp8(float x) {
  return (unsigned char)(__builtin_amdgcn_cvt_pk_fp8_f32(x, 0.f, 0, false) & 0xff);
}
__device__ __forceinline__ float fexp2(float x) { return __builtin_amdgcn_exp2f(x); }
__device__ __forceinline__ float frcpf(float x) { return __builtin_amdgcn_rcpf(x); }
#define LOG2E 1.44269504f
__device__ __forceinline__ float sigf(float x) {
  return frcpf(1.0f + fexp2(-LOG2E * x));
}
__device__ __forceinline__ float sig2(float x) {
  return frcpf(1.f + fexp2(-LOG2E * x));
}
__device__ __forceinline__ float tanh2(float x) {
  return 1.f - 2.f * frcpf(1.f + fexp2((2.f * LOG2E) * x));
}
__device__ __forceinline__ floatx4 mfma16(short8 a, short8 b, floatx4 c) {
  return __builtin_amdgcn_mfma_f32_16x16x32_bf16(a, b, c, 0, 0, 0);
}
__device__ __forceinline__ floatx4 mfma8(long a, long b, floatx4 c) {
  return __builtin_amdgcn_mfma_f32_16x16x32_fp8_fp8(a, b, c, 0, 0, 0);
}

// ---------------------------------------------------------------------------
// bodies for L1: probs / pack / rankhist
// ---------------------------------------------------------------------------
__device__ __forceinline__ void probs_body(
    int bb, float* sgW, float* sgas, float* sgad,
    const float* __restrict__ pred, const float* __restrict__ gW,
    const float* __restrict__ gas, const float* __restrict__ gad,
    float* __restrict__ out, float* __restrict__ wp16,
    float* __restrict__ wad, float* __restrict__ wmp, int N) {
  int tid = threadIdx.x;
  for (int i = tid; i < 400; i += 256) sgW[i] = gW[i];
  if (tid < 40) { sgas[tid] = gas[tid]; sgad[tid] = gad[tid]; }
  __syncthreads();
  int node = bb * 256 + tid;
  if (node >= N) return;
  const float* pr = pred + (size_t)node * NC;
  float p[NC];
#pragma unroll
  for (int c = 0; c < NC; c++) p[c] = pr[c];
  float pm = p[0]; int arg = 0;
#pragma unroll
  for (int c = 1; c < NC; c++) if (p[c] > pm) { pm = p[c]; arg = c; }
  float s = 0.f, prb[NC];
#pragma unroll
  for (int c = 0; c < NC; c++) { prb[c] = __expf(p[c] - pm); s += prb[c]; }
  float inv = 1.f / s;
  float ent = 0.f;
#pragma unroll
  for (int c = 0; c < NC; c++) {
    prb[c] *= inv;
    ent -= prb[c] * __logf(prb[c] + 1e-8f);
  }
  out[node] = (float)arg;
  out[(size_t)3 * N + node] = inv;
  out[(size_t)7 * N + node] = ent * (1.f / 2.302585093f);
  wmp[node] = inv;
  float xv[40];
#pragma unroll
  for (int hc = 0; hc < 40; hc++) {
    float t = 0.f;
#pragma unroll
    for (int k = 0; k < NC; k++) t += prb[k] * sgW[k * 40 + hc];
    xv[hc] = t;
  }
  float asv[4];
#pragma unroll
  for (int h = 0; h < NHEADS; h++) {
    float as = 0.f, ad = 0.f;
#pragma unroll
    for (int c = 0; c < NC; c++) { as += xv[h * 10 + c] * sgas[h * 10 + c]; ad += xv[h * 10 + c] * sgad[h * 10 + c]; }
    asv[h] = as;
    wad[(size_t)node * 4 + h] = ad;
  }
  float4* wp = (float4*)(wp16 + (size_t)node * 16);
  wp[0] = make_float4(prb[0], prb[1], prb[2], prb[3]);
  wp[1] = make_float4(prb[4], prb[5], prb[6], prb[7]);
  wp[2] = make_float4(prb[8], prb[9], asv[0], asv[1]);
  wp[3] = make_float4(asv[2], asv[3], __int_as_float(arg), 0.f);
}

__device__ __forceinline__ void pack_body(
    int bb, const float* __restrict__ whh0, const float* __restrict__ wih0,
    const float* __restrict__ wih1, const float* __restrict__ whh1,
    const float* __restrict__ cw1,
    unsigned char* __restrict__ PB1, unsigned char* __restrict__ PB2,
    unsigned short* __restrict__ PBc) {
  int idx = bb * 256 + threadIdx.x;
  if (idx < 81920) {  // PB1: 5ks*8w*4g*64*8 bytes
    int j = idx & 7, lane = (idx >> 3) & 63, rest = idx >> 9;
    int g = rest & 3, w = (rest >> 2) & 7, ks = rest >> 5;
    int k = ks * 32 + ((lane >> 4) << 3) + j;
    int u = w * 16 + (lane & 15), row = g * 128 + u;
    float val = 0.f;
    if (k < 128) val = whh0[row * 128 + k];
    else if (k < 138) val = wih0[row * 10 + (k - 128)];
    PB1[idx] = f2fp8(val);
  }
  if (idx < 131072) {  // PB2: 8ks*8w*4g*64*8 bytes
    int j = idx & 7, lane = (idx >> 3) & 63, rest = idx >> 9;
    int g = rest & 3, w = (rest >> 2) & 7, ks = rest >> 5;
    int k = ks * 32 + ((lane >> 4) << 3) + j;
    int u = w * 16 + (lane & 15), row = g * 128 + u;
    float val = (k < 128) ? wih1[row * 128 + k] : whh1[row * 128 + (k - 128)];
    PB2[idx] = f2fp8(val);
  }
  if (idx < 32768) {  // PBc: 8*8*64*8 bf16
    int j = idx & 7, lane = (idx >> 3) & 63, t2 = idx >> 9;
    int ti = t2 & 7, ks = t2 >> 3;
    int n = ti * 16 + (lane & 15);
    int k = ks * 32 + ((lane >> 4) << 3) + j;
    PBc[idx] = f2bf(cw1[n * 256 + k]);
  }
}

// sharded degree counters; shard = REAL blockIdx&7 (XCD affinity heuristic;
// correctness mapping-independent). atomic return = shard-local rank.
__device__ __forceinline__ void rankhist_body(
    int bb, int realblk, const int* __restrict__ ei, int* __restrict__ shin,
    int* __restrict__ shout, int* __restrict__ erank, int E, int N) {
  int idx = bb * 256 + threadIdx.x;
  if (idx >= E + N) return;
  int sh = realblk & 7;
  int src, dst;
  if (idx < E) { src = ei[idx]; dst = ei[E + idx]; } else { src = dst = idx - E; }
  int r = atomicAdd(&shin[(size_t)sh * N + dst], 1);
  atomicAdd(&shout[(size_t)sh * N + src], 1);
  erank[idx] = r;
}

// ---------------------------------------------------------------------------
// L1: probs U pack U rankhist
// ---------------------------------------------------------------------------
__global__ __launch_bounds__(256) void mega1_kernel(
    const float* __restrict__ pred, const float* __restrict__ gW,
    const float* __restrict__ gas, const float* __restrict__ gad,
    float* __restrict__ out, float* __restrict__ wp16,
    float* __restrict__ wad, float* __restrict__ wmp,
    const float* __restrict__ whh0, const float* __restrict__ wih0,
    const float* __restrict__ wih1, const float* __restrict__ whh1,
    const float* __restrict__ cw1,
    unsigned char* __restrict__ PB1, unsigned char* __restrict__ PB2,
    unsigned short* __restrict__ PBc,
    const int* __restrict__ ei, int* __restrict__ shin, int* __restrict__ shout,
    int* __restrict__ erank, int N, int E, int GP, int GK) {
  __shared__ float sgW[400], sgas[40], sgad[40];
  int b = blockIdx.x;
  if (b < GP) {
    probs_body(b, sgW, sgas, sgad, pred, gW, gas, gad, out, wp16, wad, wmp, N);
  } else if (b < GP + GK) {
    pack_body(b - GP, whh0, wih0, wih1, whh1, cw1, PB1, PB2, PBc);
  } else {
    rankhist_body(b - GP - GK, b, ei, shin, shout, erank, E, N);
  }
}

// ---------------------------------------------------------------------------
// bodies for L2: conf / scan1
// ---------------------------------------------------------------------------
__device__ __forceinline__ void conf_body(
    int bb, unsigned short* astage,
    const float* __restrict__ emb, const unsigned short* __restrict__ PBc,
    const float* __restrict__ cb1, const float* __restrict__ cw2,
    const float* __restrict__ cb2, float* __restrict__ wec, int N) {
  int tid = threadIdx.x;
  int base = bb * 128;
  for (int i = tid * 4; i < 128 * 256; i += 1024) {
    int row = i >> 8, col = i & 255;
    float4 v = make_float4(0.f, 0.f, 0.f, 0.f);
    if (base + row < N) v = *(const float4*)(emb + (size_t)(base + row) * 256 + col);
    unsigned short* d = &astage[row * 264 + col];
    d[0] = f2bf(v.x); d[1] = f2bf(v.y); d[2] = f2bf(v.z); d[3] = f2bf(v.w);
  }
  __syncthreads();
  int wave = tid >> 6, lane = tid & 63, quad = lane >> 4, ln = lane & 15;
  float b1f[8], w2f[8];
#pragma unroll
  for (int t = 0; t < 8; t++) { b1f[t] = cb1[t * 16 + ln]; w2f[t] = cw2[t * 16 + ln]; }
  floatx4 acc[2][8];
#pragma unroll
  for (int mi = 0; mi < 2; mi++)
#pragma unroll
    for (int t = 0; t < 8; t++) acc[mi][t] = (floatx4){b1f[t], b1f[t], b1f[t], b1f[t]};
#pragma unroll
  for (int ks = 0; ks < 8; ks++) {
    short8 a0 = *(const short8*)&astage[(wave * 32 + ln) * 264 + ks * 32 + quad * 8];
    short8 a1 = *(const short8*)&astage[(wave * 32 + 16 + ln) * 264 + ks * 32 + quad * 8];
    const unsigned short* bp = PBc + (((size_t)(ks * 8) * 64 + lane) << 3);
#pragma unroll
    for (int t = 0; t < 8; t++) {
      short8 b = *(const short8*)(bp + (size_t)t * 512);
      acc[0][t] = mfma16(a0, b, acc[0][t]);
      acc[1][t] = mfma16(a1, b, acc[1][t]);
    }
  }
  float part[2][4];
#pragma unroll
  for (int mi = 0; mi < 2; mi++)
#pragma unroll
    for (int r = 0; r < 4; r++) {
      float t = 0.f;
#pragma unroll
      for (int ti = 0; ti < 8; ti++) t += fmaxf(acc[mi][ti][r], 0.f) * w2f[ti];
      part[mi][r] = t;
    }
#pragma unroll
  for (int off = 8; off >= 1; off >>= 1)
#pragma unroll
    for (int mi = 0; mi < 2; mi++)
#pragma unroll
      for (int r = 0; r < 4; r++) part[mi][r] += __shfl_xor(part[mi][r], off);
  if (ln == 0) {
    float b2 = cb2[0];
#pragma unroll
    for (int mi = 0; mi < 2; mi++)
#pragma unroll
      for (int r = 0; r < 4; r++) {
        int node = base + wave * 32 + mi * 16 + quad * 4 + r;
        if (node < N) wec[node] = sigf(part[mi][r] + b2);
      }
  }
}

// per-1024 block: sum 8 in-shards -> shard prefixes (shbase) + node total;
// 8 out-shards -> outdeg. Block-local exclusive prefix -> rowptr.
__device__ __forceinline__ void scan1_body(
    int bb, int* wsum, const int* __restrict__ shin, const int* __restrict__ shout,
    int* __restrict__ shbase, int* __restrict__ outdeg,
    int* __restrict__ rowptr, int* __restrict__ partials, int N) {
  int t = threadIdx.x;
  int base = bb * 1024 + t * 4;
  int tot[4];
#pragma unroll
  for (int j = 0; j < 4; j++) {
    int i = base + j;
    int run = 0;
    if (i < N) {
      int od = 0;
#pragma unroll
      for (int sh = 0; sh < 8; sh++) {
        int v = shin[(size_t)sh * N + i];
        shbase[(size_t)sh * N + i] = run;   // intra-node shard prefix (no rowptr)
        run += v;
        od += shout[(size_t)sh * N + i];
      }
      outdeg[i] = od;
    }
    tot[j] = run;
  }
  int tsum = tot[0] + tot[1] + tot[2] + tot[3];
  int lane = t & 63, wv = t >> 6;
  int x = tsum;
#pragma unroll
  for (int d = 1; d < 64; d <<= 1) { int y = __shfl_up(x, d); if (lane >= d) x += y; }
  if (lane == 63) wsum[wv] = x;
  __syncthreads();
  int wo = 0;
  for (int i = 0; i < wv; i++) wo += wsum[i];
  int excl = wo + x - tsum;
  if (base + 0 < N) rowptr[base + 0] = excl;
  if (base + 1 < N) rowptr[base + 1] = excl + tot[0];
  if (base + 2 < N) rowptr[base + 2] = excl + tot[0] + tot[1];
  if (base + 3 < N) rowptr[base + 3] = excl + tot[0] + tot[1] + tot[2];
  if (t == 255) partials[bb] = wo + x;  // block total
}

// ---------------------------------------------------------------------------
// L2: conf U scan1
// ---------------------------------------------------------------------------
__global__ __launch_bounds__(256) void mega2_kernel(
    const float* __restrict__ emb, const unsigned short* __restrict__ PBc,
    const float* __restrict__ cb1, const float* __restrict__ cw2,
    const float* __restrict__ cb2, float* __restrict__ wec,
    const int* __restrict__ shin, const int* __restrict__ shout,
    int* __restrict__ shbase, int* __restrict__ outdeg,
    int* __restrict__ rowptr, int* __restrict__ partials, int N, int GC) {
  __shared__ __align__(16) unsigned short astage[128 * 264];
  int b = blockIdx.x;
  if (b < GC) {
    conf_body(b, astage, emb, PBc, cb1, cw2, cb2, wec, N);
  } else {
    scan1_body(b - GC, (int*)astage, shin, shout, shbase, outdeg, rowptr, partials, N);
  }
}

__global__ void scan2_kernel(int* __restrict__ partials, int nb) {
  int t = threadIdx.x;
  int lane = t & 63, wv = t >> 6;
  int v = (t < nb) ? partials[t] : 0;
  int x = v;
#pragma unroll
  for (int d = 1; d < 64; d <<= 1) { int y = __shfl_up(x, d); if (lane >= d) x += y; }
  __shared__ int wsum[4];
  if (lane == 63) wsum[wv] = x;
  __syncthreads();
  int wo = 0;
  for (int i = 0; i < wv; i++) wo += wsum[i];
  if (t < nb) partials[t] = wo + x - v;  // exclusive
}

// rowptr-only finalize (shbase left as raw prefixes; scatterrank adds rowptr)
__global__ void scan3_kernel(int* __restrict__ rowptr,
                             const int* __restrict__ partials, int N, int total) {
  int i = blockIdx.x * 256 + threadIdx.x;
  if (i < N) rowptr[i] = rowptr[i] + partials[i >> 10];
  if (i == 0) rowptr[N] = total;
}

// ---------------------------------------------------------------------------
// K-scatterrank: pos = rowptr[dst] + shbase_prefix[sh][dst] + rank. No atomics.
// sh must replicate mega1's rankhist shard: (GPK + (idx>>8)) & 7.
// ---------------------------------------------------------------------------
__global__ void scatterrank_kernel(const int* __restrict__ ei,
                                   const int* __restrict__ rowptr,
                                   const int* __restrict__ shbase,
                                   const int* __restrict__ erank,
                                   int* __restrict__ csr, int E, int N, int GPK) {
  int idx = blockIdx.x * 256 + threadIdx.x;
  if (idx >= E + N) return;
  int sh = (GPK + (idx >> 8)) & 7;
  int src, dst;
  if (idx < E) { src = ei[idx]; dst = ei[E + idx]; } else { src = dst = idx - E; }
  csr[rowptr[dst] + shbase[(size_t)sh * N + dst] + erank[idx]] = src;
}

// ---------------------------------------------------------------------------
// K-gather: 4 lanes/node; each lane all 4 heads from ONE 64B wp16 record.
// ---------------------------------------------------------------------------
__global__ __launch_bounds__(256) void gather_kernel(
    const int* __restrict__ rowptr, const int* __restrict__ csr,
    const float* __restrict__ wp16, const float* __restrict__ wad,
    const int* __restrict__ outdeg, const float* __restrict__ gW,
    const float* __restrict__ gb, float* __restrict__ wgc,
    float* __restrict__ wag, int N) {
  __shared__ float sgW[400];
  int tid = threadIdx.x;
  for (int i = tid; i < 400; i += 256) sgW[i] = gW[i];
  __syncthreads();
  int vgid = blockIdx.x * 256 + tid;
  int node = vgid >> 2, par = vgid & 3;
  if (node >= N) return;
  int beg = rowptr[node], end = rowptr[node + 1];
  float4 ad4 = *(const float4*)(wad + (size_t)node * 4);
  const float4* myrec = (const float4*)(wp16 + (size_t)node * 16);
  float4 m3 = myrec[3];
  int mylab = __float_as_int(m3.z);
  float ssum0 = 0.f, ssum1 = 0.f, ssum2 = 0.f, ssum3 = 0.f, cnt = 0.f;
  float z[4][10];
#pragma unroll
  for (int h = 0; h < 4; h++)
#pragma unroll
    for (int c = 0; c < 10; c++) z[h][c] = 0.f;
  for (int e = beg + par; e < end; e += 4) {
    int s = csr[e];
    const float4* rp = (const float4*)(wp16 + (size_t)s * 16);
    float4 r0 = rp[0], r1 = rp[1], r2 = rp[2], r3 = rp[3];
    float p[10] = {r0.x, r0.y, r0.z, r0.w, r1.x, r1.y, r1.z, r1.w, r2.x, r2.y};
    float as[4] = {r2.z, r2.w, r3.x, r3.y};
    float adh[4] = {ad4.x, ad4.y, ad4.z, ad4.w};
    cnt += (__float_as_int(r3.z) == mylab) ? 1.f : 0.f;
#pragma unroll
    for (int h = 0; h < 4; h++) {
      float v = as[h] + adh[h];
      float lr = v >= 0.f ? v : 0.2f * v;
      float ex = fexp2(LOG2E * lr);
      if (h == 0) ssum0 += ex; else if (h == 1) ssum1 += ex;
      else if (h == 2) ssum2 += ex; else ssum3 += ex;
#pragma unroll
      for (int c = 0; c < 10; c++) z[h][c] += ex * p[c];
    }
  }
#pragma unroll
  for (int mask = 1; mask <= 2; mask <<= 1) {
    cnt += __shfl_xor(cnt, mask);
    ssum0 += __shfl_xor(ssum0, mask); ssum1 += __shfl_xor(ssum1, mask);
    ssum2 += __shfl_xor(ssum2, mask); ssum3 += __shfl_xor(ssum3, mask);
#pragma unroll
    for (int h = 0; h < 4; h++)
#pragma unroll
      for (int c = 0; c < 10; c++) z[h][c] += __shfl_xor(z[h][c], mask);
  }
  float zp[10], sp;
  if (par == 0) { sp = ssum0;
#pragma unroll
    for (int c = 0; c < 10; c++) zp[c] = z[0][c];
  } else if (par == 1) { sp = ssum1;
#pragma unroll
    for (int c = 0; c < 10; c++) zp[c] = z[1][c];
  } else if (par == 2) { sp = ssum2;
#pragma unroll
    for (int c = 0; c < 10; c++) zp[c] = z[2][c];
  } else { sp = ssum3;
#pragma unroll
    for (int c = 0; c < 10; c++) zp[c] = z[3][c];
  }
  float inv = 1.f / (sp + 1e-16f);
  float gpart[10];
#pragma unroll
  for (int c = 0; c < 10; c++) {
    float t = 0.f;
#pragma unroll
    for (int k = 0; k < 10; k++) t += zp[k] * sgW[k * 40 + par * 10 + c];
    gpart[c] = t * inv;
  }
#pragma unroll
  for (int c = 0; c < 10; c++) {
    gpart[c] += __shfl_xor(gpart[c], 1);
    gpart[c] += __shfl_xor(gpart[c], 2);
  }
  if (par == 0) {
    float4 m0 = myrec[0], m1 = myrec[1], m2 = myrec[2];
    float pn[10] = {m0.x, m0.y, m0.z, m0.w, m1.x, m1.y, m1.z, m1.w, m2.x, m2.y};
    float num = 0.f, np2 = 0.f, ng2 = 0.f;
#pragma unroll
    for (int c = 0; c < 10; c++) {
      float g = gpart[c] * 0.25f + gb[c];
      float p = pn[c];
      num += p * g;
      np2 += p * p;
      ng2 += g * g;
    }
    float den = fmaxf(sqrtf(np2) * sqrtf(ng2), 1e-8f);
    wgc[node] = (num / den + 1.f) * 0.5f;
    float dgv = (float)outdeg[node];
    wag[node] = cnt / (dgv + 1e-8f);
  }
}

// ---------------------------------------------------------------------------
// K-lstm v16: (512,4) forced 2-blocks/CU. Register diet:
//   w1r -> JIT volatile L2 loads; w2r ks>=4 -> JIT volatile; biases -> sbias
//   LDS; xa -> xbuf re-read. w2r ks=0..3 + c/s-state remain register-resident.
// ---------------------------------------------------------------------------
#define HB2 4352  // 32*136

__global__ __launch_bounds__(512, 4) void lstm_kernel(
    const float* __restrict__ pred, const unsigned char* __restrict__ PB1,
    const unsigned char* __restrict__ PB2,
    const float* __restrict__ bih0, const float* __restrict__ bhh0,
    const float* __restrict__ bih1, const float* __restrict__ bhh1,
    const float* __restrict__ wmp, const float* __restrict__ wec,
    const float* __restrict__ wgc, const float* __restrict__ wag,
    float* __restrict__ out, int N) {
  __shared__ __align__(16) unsigned char hb[4 * HB2];   // 17408
  __shared__ __align__(16) unsigned char xbuf[32 * 40]; // 1280
  __shared__ float sbias[1024];                         // 4096: [layer*512+row]
  __shared__ float varsum[32];
  int tid = threadIdx.x;
  int base = blockIdx.x * 32;
  for (int i = tid * 4; i < HB2; i += 2048) *(int*)&hb[3 * HB2 + i] = 0;  // h2[-1]=0
  for (int i = tid; i < 32 * 40; i += 512) {
    int nd = i / 40, o = i - nd * 40;
    float v = 0.f;
    if (o < 10 && base + nd < N) v = pred[(size_t)(base + nd) * NC + o];
    xbuf[i] = f2fp8(v);
  }
  sbias[tid] = bih0[tid] + bhh0[tid];
  sbias[512 + tid] = bih1[tid] + bhh1[tid];
  if (tid < 32) varsum[tid] = 0.f;
  int wave = tid >> 6, lane = tid & 63, quad = lane >> 4, ln = lane & 15;
  // w2 low half (ks=0..3) register-resident; everything else streamed
  long w2r[4][4];
#pragma unroll
  for (int ks = 0; ks < 4; ks++)
#pragma unroll
    for (int g = 0; g < 4; g++)
      w2r[ks][g] = *(const long*)(PB2 + (size_t)(((ks * 8 + wave) * 4 + g) * 64 + lane) * 8);
  float c1[8], c2[8], s1[8], s2[8];
#pragma unroll
  for (int i = 0; i < 8; i++) { c1[i] = 0.f; c2[i] = 0.f; s1[i] = 0.f; s2[i] = 0.f; }
  const int hq = quad * 8;
  const int ucol = wave * 16 + ln;
  int arow[2], wrow[2];
#pragma unroll
  for (int mt = 0; mt < 2; mt++) {
    arow[mt] = (mt * 16 + ln) * 136 + hq;
    wrow[mt] = (mt * 16 + quad * 4) * 136 + ucol;
  }
  __syncthreads();  // xbuf + sbias + hb ready

  // ----- prime: phase1(t=0), h1 state = 0 -> x term + bias only -----
  {
    long xa0 = *(const long*)&xbuf[ln * 40 + hq];
    long xa1 = *(const long*)&xbuf[(16 + ln) * 40 + hq];
    floatx4 acc[2][4];
#pragma unroll
    for (int g = 0; g < 4; g++) {
      float b0 = sbias[g * 128 + ucol];
      acc[0][g] = (floatx4){b0, b0, b0, b0};
      acc[1][g] = (floatx4){b0, b0, b0, b0};
    }
#pragma unroll
    for (int g = 0; g < 4; g++) {
      long wv = *(const long*)(PB1 + (size_t)(((4 * 8 + wave) * 4 + g) * 64 + lane) * 8);
      acc[0][g] = mfma8(xa0, wv, acc[0][g]);
      acc[1][g] = mfma8(xa1, wv, acc[1][g]);
    }
#pragma unroll
    for (int mt = 0; mt < 2; mt++)
#pragma unroll
      for (int r = 0; r < 4; r++) {
        int ci = mt * 4 + r;
        float ig = sig2(acc[mt][0][r]);
        float gg = tanh2(acc[mt][2][r]);
        float og = sig2(acc[mt][3][r]);
        float c = ig * gg;
        c1[ci] = c;
        hb[0 + wrow[mt] + r * 136] = f2fp8(og * tanh2(c));
      }
  }

// Segment: barrier; phase2(t) [O1R=h1[t], O2R=h2[t-1] -> O2W=h2[t]];
//          then (unless last) phase1(t+1) [O1R + x -> O1W=h1[t+1]].
// Weights ks>=4 (phase2) and all of phase1's w1 are JIT volatile L2 loads.
#define LSTM_SEG(O1R, O1W, O2R, O2W, lastseg)                                    \
  {                                                                              \
    __syncthreads();                                                             \
    floatx4 acc[2][4];                                                           \
    _Pragma("unroll") for (int g = 0; g < 4; g++) {                              \
      float b1 = sbias[512 + g * 128 + ucol];                                    \
      acc[0][g] = (floatx4){b1, b1, b1, b1};                                     \
      acc[1][g] = (floatx4){b1, b1, b1, b1};                                     \
    }                                                                            \
    _Pragma("unroll") for (int ks = 0; ks < 8; ks++) {                           \
      long a0_, a1_;                                                             \
      if (ks < 4) {                                                              \
        a0_ = *(const long*)&hb[(O1R) + arow[0] + ks * 32];                      \
        a1_ = *(const long*)&hb[(O1R) + arow[1] + ks * 32];                      \
      } else {                                                                   \
        a0_ = *(const long*)&hb[(O2R) + arow[0] + (ks - 4) * 32];                \
        a1_ = *(const long*)&hb[(O2R) + arow[1] + (ks - 4) * 32];                \
      }                                                                          \
      _Pragma("unroll") for (int g = 0; g < 4; g++) {                            \
        long wv;                                                                 \
        if (ks < 4) wv = w2r[ks][g];                                             \
        else wv = *(volatile const long*)(PB2 +                                  \
                 (size_t)(((ks * 8 + wave) * 4 + g) * 64 + lane) * 8);           \
        acc[0][g] = mfma8(a0_, wv, acc[0][g]);                                   \
        acc[1][g] = mfma8(a1_, wv, acc[1][g]);                                   \
      }                                                                          \
    }                                                                            \
    _Pragma("unroll") for (int mt = 0; mt < 2; mt++)                             \
        _Pragma("unroll") for (int r = 0; r < 4; r++) {                          \
      int ci = mt * 4 + r;                                                       \
      float ig = sig2(acc[mt][0][r]);                                            \
      float fg = sig2(acc[mt][1][r]);                                            \
      float gg = tanh2(acc[mt][2][r]);                                           \
      float og = sig2(acc[mt][3][r]);                                            \
      float c = fg * c2[ci] + ig * gg;                                           \
      c2[ci] = c;                                                                \
      float h = og * tanh2(c);                                                   \
      s1[ci] += h;                                                               \
      s2[ci] += h * h;                                                           \
      hb[(O2W) + wrow[mt] + r * 136] = f2fp8(h);                                 \
    }                                                                            \
    if (!(lastseg)) {                                                            \
      _Pragma("unroll") for (int g = 0; g < 4; g++) {                            \
        float b0 = sbias[g * 128 + ucol];                                        \
        acc[0][g] = (floatx4){b0, b0, b0, b0};                                   \
        acc[1][g] = (floatx4){b0, b0, b0, b0};                                   \
      }                                                                          \
      _Pragma("unroll") for (int ks = 0; ks < 5; ks++) {                         \
        long a0_, a1_;                                                           \
        if (ks < 4) {                                                            \
          a0_ = *(const long*)&hb[(O1R) + arow[0] + ks * 32];                    \
          a1_ = *(const long*)&hb[(O1R) + arow[1] + ks * 32];                    \
        } else {                                                                 \
          a0_ = *(const long*)&xbuf[ln * 40 + hq];                               \
          a1_ = *(const long*)&xbuf[(16 + ln) * 40 + hq];                        \
        }                                                                        \
        _Pragma("unroll") for (int g = 0; g < 4; g++) {                          \
          long wv = *(volatile const long*)(PB1 +                                \
                   (size_t)(((ks * 8 + wave) * 4 + g) * 64 + lane) * 8);         \
          acc[0][g] = mfma8(a0_, wv, acc[0][g]);                                 \
          acc[1][g] = mfma8(a1_, wv, acc[1][g]);                                 \
        }                                                                        \
      }                                                                          \
      _Pragma("unroll") for (int mt = 0; mt < 2; mt++)                           \
          _Pragma("unroll") for (int r = 0; r < 4; r++) {                        \
        int ci = mt * 4 + r;                                                     \
        float ig = sig2(acc[mt][0][r]);                                          \
        float fg = sig2(acc[mt][1][r]);                                          \
        float gg = tanh2(acc[mt][2][r]);                                         \
        float og = sig2(acc[mt][3][r]);                                          \
        float c = fg * c1[ci] + ig * gg;                                         \
        c1[ci] = c;                                                              \
        hb[(O1W) + wrow[mt] + r * 136] = f2fp8(og * tanh2(c));                   \
      }                                                                          \
    }                                                                            \
  }

  for (int tt = 0; tt < TSTEPS / 2; tt++) {
    LSTM_SEG(0, HB2, 3 * HB2, 2 * HB2, false);
    LSTM_SEG(HB2, 0, 2 * HB2, 3 * HB2, tt == TSTEPS / 2 - 1);
  }
#undef LSTM_SEG

  // variance (ddof=1) per (node,unit), summed over 128 units via LDS atomics
#pragma unroll
  for (int mt = 0; mt < 2; mt++)
#pragma unroll
    for (int r = 0; r < 4; r++) {
      int ci = mt * 4 + r;
      float m = s1[ci] * (1.f / 12.f);
      float var = (s2[ci] - 12.f * m * m) * (1.f / 11.f);
      atomicAdd(&varsum[mt * 16 + quad * 4 + r], var);
    }
  __syncthreads();
  // fused combine tail
  if (tid < 32 && base + tid < N) {
    int node = base + tid;
    float tc = 1.f / (1.f + varsum[tid] * (1.f / 128.f));
    float mp = wmp[node], ec = wec[node], gc = wgc[node];
    float comb = 0.4f * mp + 0.2f * ec + 0.2f * tc + 0.2f * gc;
    bool mask = (comb > 0.85f) && (wag[node] >= 0.6f);
    out[(size_t)1 * N + node] = comb;
    out[(size_t)2 * N + node] = mask ? 1.f : 0.f;
    out[(size_t)4 * N + node] = ec;
    out[(size_t)5 * N + node] = tc;
    out[(size_t)6 * N + node] = gc;
  }
}

// ---------------------------------------------------------------------------
extern "C" void kernel_launch(void* const* d_in, const int* in_sizes, int n_in,
                              void* d_out, int out_size, void* d_ws, size_t ws_size,
                              hipStream_t stream) {
  const float* emb  = (const float*)d_in[0];
  const float* pred = (const float*)d_in[1];
  const int*   ei   = (const int*)d_in[3];
  const float* cw1  = (const float*)d_in[4];
  const float* cb1  = (const float*)d_in[5];
  const float* cw2  = (const float*)d_in[6];
  const float* cb2  = (const float*)d_in[7];
  const float* wih0 = (const float*)d_in[8];
  const float* whh0 = (const float*)d_in[9];
  const float* bih0 = (const float*)d_in[10];
  const float* bhh0 = (const float*)d_in[11];
  const float* wih1 = (const float*)d_in[12];
  const float* whh1 = (const float*)d_in[13];
  const float* bih1 = (const float*)d_in[14];
  const float* bhh1 = (const float*)d_in[15];
  const float* gW   = (const float*)d_in[16];
  const float* gas  = (const float*)d_in[17];
  const float* gad  = (const float*)d_in[18];
  const float* gb   = (const float*)d_in[19];

  const int N = in_sizes[0] / HIDN;
  const int E = in_sizes[3] / 2;
  float* out = (float*)d_out;
  float* ws = (float*)d_ws;
  const size_t sN = (size_t)N;
  const size_t sE = (size_t)E;

  float* wp16   = ws;                          // 16N (64B records)
  float* wad    = ws + 16 * sN;                // 4N
  float* wmp    = ws + 20 * sN;                // N
  float* wec    = ws + 21 * sN;                // N
  float* wgc    = ws + 22 * sN;                // N
  float* wag    = ws + 23 * sN;                // N
  int* outdeg   = (int*)(ws + 24 * sN);        // N
  int* rowptr   = (int*)(ws + 25 * sN);        // N+1 (+pad 64)
  int* shin     = (int*)(ws + 26 * sN) + 64;   // 8N  <- memset start (16N ints)
  int* shout    = shin + 8 * sN;               // 8N  <- memset end
  int* shbase   = shout + 8 * sN;              // 8N
  int* partials = shbase + 8 * sN + 64;        // 256
  int* erank    = partials + 256 + 64;         // E+N
  int* csr      = erank + sE + sN + 64;        // E+N
  float* pbase  = (float*)(csr + sE + sN + 64);
  unsigned char* PB1 = (unsigned char*)pbase;                  // 81920 B
  unsigned char* PB2 = (unsigned char*)(pbase + 20480);        // 131072 B
  unsigned short* PBc = (unsigned short*)(pbase + 53248);      // 32768 ushort

  hipMemsetAsync(shin, 0, 16 * sN * sizeof(int), stream);

  // L1: probs U pack U rankhist
  int GP = (N + 255) / 256, GK = 512;
  int ne = E + N;
  int GH = (ne + 255) / 256;
  mega1_kernel<<<GP + GK + GH, 256, 0, stream>>>(
      pred, gW, gas, gad, out, wp16, wad, wmp,
      whh0, wih0, wih1, whh1, cw1, PB1, PB2, PBc,
      ei, shin, shout, erank, N, E, GP, GK);

  // L2: conf U scan1
  int GC = (N + 127) / 128;
  int nb = (N + 1023) / 1024;
  mega2_kernel<<<GC + nb, 256, 0, stream>>>(
      emb, PBc, cb1, cw2, cb2, wec, shin, shout, shbase, outdeg, rowptr,
      partials, N, GC);

  scan2_kernel<<<1, 256, 0, stream>>>(partials, nb);
  scan3_kernel<<<(N + 255) / 256, 256, 0, stream>>>(rowptr, partials, N, ne);

  scatterrank_kernel<<<(ne + 255) / 256, 256, 0, stream>>>(
      ei, rowptr, shbase, erank, csr, E, N, GP + GK);

  gather_kernel<<<(4 * N + 255) / 256, 256, 0, stream>>>(
      rowptr, csr, wp16, wad, outdeg, gW, gb, wgc, wag, N);

  lstm_kernel<<<(N + 31) / 32, 512, 0, stream>>>(
      pred, PB1, PB2, bih0, bhh0, bih1, bhh1, wmp, wec, wgc, wag, out, N);
}